// Round 2
// baseline (73.134 us; speedup 1.0000x reference)
//
#include <hip/hip_runtime.h>

// NCC loss, streaming: full-row C=8, (I,J)-packed fp16, YB=8 / 2 waves/SIMD.
// I,J fp32 (32,1,512,512), 9x9 box, zero-pad, /81. History: R21 42.3us at
// YB=16 (grid 1024 = #SIMDs, 1 wave/SIMD, VALUBusy 16%, latency-bound at
// ~2900 cyc/step). R22 (prefetch ring D=6) FAILED: scheduler sank issues to
// uses (VGPR 176 not ~230, VALUBusy flat) -> ILP depth is not controllable
// from HIP source here. R23: get overlap from TLP instead — YB=8, NBAND=64,
// grid 2048 = 2 waves/SIMD; HW interleaves the two waves' stalls. Per-wave
// 24 steps (16 warmup + 8 outputs), prefetch parity-1 (R21 proven), full
// unroll -> k%9 ring slots, buffer parity, and last-issue guard all static.
// Row traffic 1.5x (L2 absorbs halo; HBM fetch stays near-ideal ~67MB).
// DPP bound_ctrl edge zeros == image zero-padding (no masks); cross-term via
// d*swap(d); rings store rounded h2 once (add==evict bits -> telescoping).

constexpr int BATCH = 32;
constexpr int H = 512, W = 512;
constexpr int YB = 8;
constexpr int NBAND = H / YB;  // 64
constexpr int NSTEP = YB + 16; // 24: raw rows yb-8 .. yb+15
constexpr float EPS81 = 81.0f * 81.0f * 1e-5f;  // ncc = R^2/(P*Q+EPS81)

using h2 = __attribute__((ext_vector_type(2))) _Float16;

__global__ void zero_accum(float* ws) { ws[0] = 0.0f; }

__device__ __forceinline__ h2 up1(h2 x) {  // lane i <- i-1 (wave_shr:1), edge=0
  return __builtin_bit_cast(
      h2, __builtin_amdgcn_update_dpp(0, __builtin_bit_cast(int, x), 0x138, 0xF,
                                      0xF, true));
}
__device__ __forceinline__ h2 dn1(h2 x) {  // lane i <- i+1 (wave_shl:1), edge=0
  return __builtin_bit_cast(
      h2, __builtin_amdgcn_update_dpp(0, __builtin_bit_cast(int, x), 0x130, 0xF,
                                      0xF, true));
}
// pack (I,J) -> h2 (RTZ) then AND-mask (wave-uniform y zero-pad)
__device__ __forceinline__ h2 pkm(float lo, float hi, unsigned m) {
  const unsigned u =
      __builtin_bit_cast(unsigned, __builtin_amdgcn_cvt_pkrtz(lo, hi)) & m;
  return __builtin_bit_cast(h2, u);
}
__device__ __forceinline__ h2 swp(h2 x) {  // swap halves (folds to op_sel)
  return __builtin_shufflevector(x, x, 1, 0);
}

// 9-tap centered window sums, 8 contiguous cols/lane (whole 512-col row).
__device__ __forceinline__ void tap8(const h2 u[8], h2 O[8]) {
  const h2 P0 = u[0], P1 = P0 + u[1], P2 = P1 + u[2], P3 = P2 + u[3],
           P4 = P3 + u[4], P5 = P4 + u[5], P6 = P5 + u[6], T = P6 + u[7];
  const h2 UP3 = up1(P3), UP4 = up1(P4), UP5 = up1(P5), UP6 = up1(P6), UT = up1(T);
  const h2 DP0 = dn1(P0), DP1 = dn1(P1), DP2 = dn1(P2), DP3 = dn1(P3);
  O[0] = (UT - UP3) + P4;
  O[1] = (UT - UP4) + P5;
  O[2] = (UT - UP5) + P6;
  O[3] = (UT - UP6) + T;
  O[4] = T + DP0;
  O[5] = (T - P0) + DP1;
  O[6] = (T - P1) + DP2;
  O[7] = (T - P2) + DP3;
}

__global__ __launch_bounds__(64, 2) void ncc_stream(const float* __restrict__ I,
                                                    const float* __restrict__ J,
                                                    float* __restrict__ accum) {
  const int lane = threadIdx.x;
  const int blk = blockIdx.x;
  const int band = blk & (NBAND - 1);
  const int b = blk >> 6;  // batch 0..31
  const int yb = band * YB;
  const int x0 = 8 * lane;
  const h2 zero2 = {_Float16(0.0f), _Float16(0.0f)};
  const h2 ninv81 = {_Float16(-1.0f / 81.0f), _Float16(-1.0f / 81.0f)};

  const float* __restrict__ Ib = I + (size_t)b * (H * W);
  const float* __restrict__ Jb = J + (size_t)b * (H * W);

  // mod-9 rings (packed I,J), all indices compile-time in the unrolled body
  h2 rg[9][8];   // raw ring: (I, J)
  h2 d9[9][8];   // dI/dJ ring: (dI, dJ)
  h2 V[8];       // running vertical sum of raw
  h2 vpq[8];     // (sum dI^2, sum dJ^2)
  h2 vr[8];      // (sum dI*dJ, same)
#pragma unroll
  for (int s = 0; s < 9; ++s)
#pragma unroll
    for (int c = 0; c < 8; ++c) { rg[s][c] = zero2; d9[s][c] = zero2; }
#pragma unroll
  for (int c = 0; c < 8; ++c) { V[c] = zero2; vpq[c] = zero2; vr[c] = zero2; }
  float acc = 0.f;

  // prefetch buffers, parity-indexed (static after unroll)
  float4 bI0[2], bI1[2], bJ0[2], bJ1[2];
  {
    const int y0 = yb - 8;
    const int yc0 = y0 < 0 ? 0 : y0;  // y0 <= H-1-... no upper clamp needed
    const int off0 = yc0 * W + x0;
    bI0[0] = *reinterpret_cast<const float4*>(Ib + off0);
    bI1[0] = *reinterpret_cast<const float4*>(Ib + off0 + 4);
    bJ0[0] = *reinterpret_cast<const float4*>(Jb + off0);
    bJ1[0] = *reinterpret_cast<const float4*>(Jb + off0 + 4);
  }

  // k=0..23: y = yb-8+k. k>=8: stage1 at m=y-4. k>=16: stage2 + output o=y-8.
#pragma unroll
  for (int k = 0; k < NSTEP; ++k) {
    const int si = k % 9;          // data ring slot (static)
    const int t = (si + 5) % 9;    // center slot (static)
    const int cur = k & 1, nxt = cur ^ 1;  // buffer parity (static)
    const int y = yb - 8 + k;
    const unsigned msk = ((y >= 0) & (y < H)) ? 0xFFFFFFFFu : 0u;

    // 0) ISSUE next step's loads (clamped row addr) -> consumed next step.
    //    k==NSTEP-1 has no next step: guard is compile-time static.
    if (k < NSTEP - 1) {
      const int yn = y + 1;
      const int ycn = yn < 0 ? 0 : (yn > H - 1 ? H - 1 : yn);
      const int offn = ycn * W + x0;
      bI0[nxt] = *reinterpret_cast<const float4*>(Ib + offn);
      bI1[nxt] = *reinterpret_cast<const float4*>(Ib + offn + 4);
      bJ0[nxt] = *reinterpret_cast<const float4*>(Jb + offn);
      bJ1[nxt] = *reinterpret_cast<const float4*>(Jb + offn + 4);
    }

    // 1) consume current buffers: pack (I,J), AND-mask y-pad
    h2 na[8];
    na[0] = pkm(bI0[cur].x, bJ0[cur].x, msk);
    na[1] = pkm(bI0[cur].y, bJ0[cur].y, msk);
    na[2] = pkm(bI0[cur].z, bJ0[cur].z, msk);
    na[3] = pkm(bI0[cur].w, bJ0[cur].w, msk);
    na[4] = pkm(bI1[cur].x, bJ1[cur].x, msk);
    na[5] = pkm(bI1[cur].y, bJ1[cur].y, msk);
    na[6] = pkm(bI1[cur].z, bJ1[cur].z, msk);
    na[7] = pkm(bI1[cur].w, bJ1[cur].w, msk);

    // 2) vertical running sum: evict slot si (row y-9), write new
#pragma unroll
    for (int c = 0; c < 8; ++c) {
      V[c] += na[c] - rg[si][c];
      rg[si][c] = na[c];
    }

    if (k >= 8) {
      const int m = y - 4;
      if ((m >= 0) & (m < H)) {  // wave-uniform
        h2 M[8];
        tap8(V, M);
#pragma unroll
        for (int c = 0; c < 8; ++c) {
          const h2 d = M[c] * ninv81 + rg[t][c];  // (dI, dJ)
          const h2 o = d9[t][c];
          vpq[c] += d * d - o * o;                // (dI^2, dJ^2)
          vr[c] += d * swp(d) - o * swp(o);       // (dI*dJ, dI*dJ)
          d9[t][c] = d;
        }
      } else {  // m outside image: dI=dJ=0, eviction-only
#pragma unroll
        for (int c = 0; c < 8; ++c) {
          const h2 o = d9[t][c];
          vpq[c] -= o * o;
          vr[c] -= o * swp(o);
          d9[t][c] = zero2;
        }
      }

      if (k >= 16) {
        h2 P[8], R[8];
        tap8(vpq, P);  // (81^2 varI, 81^2 varJ) pre-scale
        tap8(vr, R);   // (81^2 cov, same)
#pragma unroll
        for (int c = 0; c < 8; ++c) {
          const float Pl = (float)P[c][0], Qh = (float)P[c][1];
          const float Rl = (float)R[c][0];
          acc += (Rl * Rl) * __builtin_amdgcn_rcpf(fmaf(Pl, Qh, EPS81));
        }
      }
    }
  }

  // wave reduction, one atomic per wave
#pragma unroll
  for (int off = 32; off > 0; off >>= 1) acc += __shfl_down(acc, off, 64);
  if (lane == 0) atomicAdd(accum, acc);
}

__global__ void finalize(const float* __restrict__ ws, float* __restrict__ out) {
  out[0] = -ws[0] * (1.0f / (float)((size_t)BATCH * H * W));
}

extern "C" void kernel_launch(void* const* d_in, const int* in_sizes, int n_in,
                              void* d_out, int out_size, void* d_ws, size_t ws_size,
                              hipStream_t stream) {
  const float* I = (const float*)d_in[0];
  const float* J = (const float*)d_in[1];
  float* out = (float*)d_out;
  float* acc = (float*)d_ws;

  zero_accum<<<1, 1, 0, stream>>>(acc);
  ncc_stream<<<BATCH * NBAND, 64, 0, stream>>>(I, J, acc);
  finalize<<<1, 1, 0, stream>>>(acc, out);
}

// Round 4
// 53.665 us; speedup vs baseline: 1.3628x; 1.3628x over previous
//
#include <hip/hip_runtime.h>
#include <utility>

// NCC loss, streaming: full-row C=8, (I,J)-packed fp16, INLINE-ASM PIPELINE v2.
// I,J fp32 (32,1,512,512), 9x9 box, zero-pad, /81.
// History: R21 42.3us (YB=16, prefetch-1 convoy, VALUBusy 16%). R22 source
// D=6 ring FAILED (compiler sank issues). R23 YB=8 2-wave FAILED (convoy is
// TLP-invariant + halo blowup). R24 asm D=6 ring FAILED NaN: ~290 VGPR
// demand > 256 forced allocator spills/copies of PENDING asm-load dests
// (allocator thinks asm outputs are defined at issue) -> stale reads.
// R25: same asm pipeline, pressure cut: d9 ring (72 VGPR) -> LDS 18KB
// ([9][2][64]x16B, lane-stride-16B = conflict-free b128; single wave, no
// barrier), PFD 6->4 (buffers 96->64). Peak ~210 VGPR -> no spills; only
// long-range spill candidates are VALU-defined rg slots (copy-safe).
// Steady 16 loads in flight, consume at literal vmcnt(12), tail 12/8/4/0;
// every waitcnt followed by sched_barrier(0) (rule #18). Volatile-asm mutual
// order pins issue schedule -> structurally un-sinkable.

constexpr int BATCH = 32;
constexpr int H = 512, W = 512;
constexpr int YB = 16;
constexpr int NBAND = H / YB;   // 32
constexpr int NSTEP = YB + 16;  // 32 raw rows yb-8 .. yb+23
constexpr int PFD = 4;          // prefetch distance (rows); 4 loads/row
constexpr float EPS81 = 81.0f * 81.0f * 1e-5f;  // ncc = R^2/(P*Q+EPS81)

using h2 = __attribute__((ext_vector_type(2))) _Float16;
using f4 = __attribute__((ext_vector_type(4))) float;
using u4 = __attribute__((ext_vector_type(4))) unsigned int;

__global__ void zero_accum(float* ws) { ws[0] = 0.0f; }

__device__ __forceinline__ h2 up1(h2 x) {  // lane i <- i-1 (wave_shr:1), edge=0
  return __builtin_bit_cast(
      h2, __builtin_amdgcn_update_dpp(0, __builtin_bit_cast(int, x), 0x138, 0xF,
                                      0xF, true));
}
__device__ __forceinline__ h2 dn1(h2 x) {  // lane i <- i+1 (wave_shl:1), edge=0
  return __builtin_bit_cast(
      h2, __builtin_amdgcn_update_dpp(0, __builtin_bit_cast(int, x), 0x130, 0xF,
                                      0xF, true));
}
// pack (I,J) -> h2 (RTZ) then AND-mask (wave-uniform y zero-pad)
__device__ __forceinline__ h2 pkm(float lo, float hi, unsigned m) {
  const unsigned u =
      __builtin_bit_cast(unsigned, __builtin_amdgcn_cvt_pkrtz(lo, hi)) & m;
  return __builtin_bit_cast(h2, u);
}
__device__ __forceinline__ h2 swp(h2 x) {  // swap halves (folds to op_sel)
  return __builtin_shufflevector(x, x, 1, 0);
}

// Two async 16B loads from p / p+16B. asm => invisible to the compiler's
// scheduler (can't be sunk to use) and waitcnt pass (no auto vmcnt(0)).
__device__ __forceinline__ void gload2(const float* p, f4& a, f4& b) {
  asm volatile(
      "global_load_dwordx4 %0, %2, off\n\t"
      "global_load_dwordx4 %1, %2, off offset:16"
      : "=&v"(a), "=&v"(b)
      : "v"(p));
}

// Hand-counted wait + rule-#18 fence (consumers may not hoist above).
template <int N>
__device__ __forceinline__ void waitcnt_vm() {
  asm volatile("s_waitcnt vmcnt(%0)" ::"i"(N) : "memory");
  __builtin_amdgcn_sched_barrier(0);
}

template <class F, int... Ks>
__device__ __forceinline__ void unroll_steps(F&& f,
                                             std::integer_sequence<int, Ks...>) {
  (f(std::integral_constant<int, Ks>{}), ...);
}

// 9-tap centered window sums, 8 contiguous cols/lane (whole 512-col row).
__device__ __forceinline__ void tap8(const h2 u[8], h2 O[8]) {
  const h2 P0 = u[0], P1 = P0 + u[1], P2 = P1 + u[2], P3 = P2 + u[3],
           P4 = P3 + u[4], P5 = P4 + u[5], P6 = P5 + u[6], T = P6 + u[7];
  const h2 UP3 = up1(P3), UP4 = up1(P4), UP5 = up1(P5), UP6 = up1(P6), UT = up1(T);
  const h2 DP0 = dn1(P0), DP1 = dn1(P1), DP2 = dn1(P2), DP3 = dn1(P3);
  O[0] = (UT - UP3) + P4;
  O[1] = (UT - UP4) + P5;
  O[2] = (UT - UP5) + P6;
  O[3] = (UT - UP6) + T;
  O[4] = T + DP0;
  O[5] = (T - P0) + DP1;
  O[6] = (T - P1) + DP2;
  O[7] = (T - P2) + DP3;
}

__global__ __launch_bounds__(64, 1) void ncc_stream(const float* __restrict__ I,
                                                    const float* __restrict__ J,
                                                    float* __restrict__ accum) {
  const int lane = threadIdx.x;
  const int blk = blockIdx.x;
  const int band = blk & (NBAND - 1);
  const int b = blk >> 5;  // batch 0..31
  const int yb = band * YB;
  const int x0 = 8 * lane;
  const h2 zero2 = {_Float16(0.0f), _Float16(0.0f)};
  const h2 ninv81 = {_Float16(-1.0f / 81.0f), _Float16(-1.0f / 81.0f)};

  const float* __restrict__ Ib = I + (size_t)b * (H * W);
  const float* __restrict__ Jb = J + (size_t)b * (H * W);

  // d9 ring lives in LDS: [slot][half][lane] x 16B. Lane-stride 16B ->
  // conflict-free ds_read_b128/ds_write_b128. Single wave: no barriers.
  __shared__ u4 d9s[9][2][64];

  // mod-9 raw ring (packed I,J) stays in VGPRs
  h2 rg[9][8];   // raw ring: (I, J)
  h2 V[8];       // running vertical sum of raw
  h2 vpq[8];     // (sum dI^2, sum dJ^2)
  h2 vr[8];      // (sum dI*dJ, same)
#pragma unroll
  for (int s = 0; s < 9; ++s)
#pragma unroll
    for (int c = 0; c < 8; ++c) rg[s][c] = zero2;
#pragma unroll
  for (int c = 0; c < 8; ++c) { V[c] = zero2; vpq[c] = zero2; vr[c] = zero2; }
  const u4 zero4 = {0u, 0u, 0u, 0u};
#pragma unroll
  for (int s = 0; s < 9; ++s) {
    d9s[s][0][lane] = zero4;
    d9s[s][1][lane] = zero4;
  }
  float acc = 0.f;

  // PFD-slot load ring; slot index K%PFD static after template unroll.
  f4 bI0[PFD], bI1[PFD], bJ0[PFD], bJ1[PFD];

  // Prologue: issue rows yb-8 .. yb-8+PFD-1 (lower clamp only; max 491).
#pragma unroll
  for (int j = 0; j < PFD; ++j) {
    const int y0 = yb - 8 + j;
    const int yc0 = y0 < 0 ? 0 : y0;
    const int off0 = yc0 * W + x0;
    gload2(Ib + off0, bI0[j], bI1[j]);
    gload2(Jb + off0, bJ0[j], bJ1[j]);
  }

  // k=0..31: y = yb-8+k. k>=8: stage1 at m=y-4. k>=16: stage2 + output o=y-8.
  unroll_steps(
      [&](auto kc) {
        constexpr int K = decltype(kc)::value;
        constexpr int si = K % 9;        // data ring slot
        constexpr int t = (si + 5) % 9;  // center slot
        constexpr int sl = K % PFD;      // load ring slot
        constexpr int REM = NSTEP - 1 - K;
        constexpr int ALW = (REM < PFD - 1 ? REM : PFD - 1) * 4;
        const int y = yb - 8 + K;
        const unsigned msk = ((y >= 0) & (y < H)) ? 0xFFFFFFFFu : 0u;

        // 0) wait until slot sl's 4 loads (issued PFD steps ago) are done;
        //    leaves ALW (steady 12) in flight.
        waitcnt_vm<ALW>();

        // 1) consume slot sl: pack (I,J), AND-mask y-pad
        h2 na[8];
        na[0] = pkm(bI0[sl].x, bJ0[sl].x, msk);
        na[1] = pkm(bI0[sl].y, bJ0[sl].y, msk);
        na[2] = pkm(bI0[sl].z, bJ0[sl].z, msk);
        na[3] = pkm(bI0[sl].w, bJ0[sl].w, msk);
        na[4] = pkm(bI1[sl].x, bJ1[sl].x, msk);
        na[5] = pkm(bI1[sl].y, bJ1[sl].y, msk);
        na[6] = pkm(bI1[sl].z, bJ1[sl].z, msk);
        na[7] = pkm(bI1[sl].w, bJ1[sl].w, msk);

        // 2) reissue slot sl for row y+PFD (clamped addr; mask fixes values)
        if constexpr (K + PFD < NSTEP) {
          const int yn = y + PFD;
          const int ycn = yn < 0 ? 0 : (yn > H - 1 ? H - 1 : yn);
          const int offn = ycn * W + x0;
          gload2(Ib + offn, bI0[sl], bI1[sl]);
          gload2(Jb + offn, bJ0[sl], bJ1[sl]);
        }

        // 3) vertical running sum: evict slot si (row y-9), write new
#pragma unroll
        for (int c = 0; c < 8; ++c) {
          V[c] += na[c] - rg[si][c];
          rg[si][c] = na[c];
        }

        if constexpr (K >= 8) {
          const int m = y - 4;
          const u4 ov0 = d9s[t][0][lane];  // old d (evicted row), c=0..3
          const u4 ov1 = d9s[t][1][lane];  // c=4..7
          if ((m >= 0) & (m < H)) {        // wave-uniform
            h2 M[8];
            tap8(V, M);
            u4 nv0, nv1;
#pragma unroll
            for (int c = 0; c < 8; ++c) {
              const h2 d = M[c] * ninv81 + rg[t][c];  // (dI, dJ)
              const h2 o =
                  __builtin_bit_cast(h2, c < 4 ? ov0[c] : ov1[c - 4]);
              vpq[c] += d * d - o * o;                // (dI^2, dJ^2)
              vr[c] += d * swp(d) - o * swp(o);       // (dI*dJ, dI*dJ)
              const unsigned du = __builtin_bit_cast(unsigned, d);
              if (c < 4) nv0[c] = du; else nv1[c - 4] = du;
            }
            d9s[t][0][lane] = nv0;
            d9s[t][1][lane] = nv1;
          } else {  // m outside image: dI=dJ=0, eviction-only
#pragma unroll
            for (int c = 0; c < 8; ++c) {
              const h2 o =
                  __builtin_bit_cast(h2, c < 4 ? ov0[c] : ov1[c - 4]);
              vpq[c] -= o * o;
              vr[c] -= o * swp(o);
            }
            d9s[t][0][lane] = zero4;
            d9s[t][1][lane] = zero4;
          }

          if constexpr (K >= 16) {
            h2 P[8], R[8];
            tap8(vpq, P);  // (81^2 varI, 81^2 varJ) pre-scale
            tap8(vr, R);   // (81^2 cov, same)
#pragma unroll
            for (int c = 0; c < 8; ++c) {
              const float Pl = (float)P[c][0], Qh = (float)P[c][1];
              const float Rl = (float)R[c][0];
              acc += (Rl * Rl) * __builtin_amdgcn_rcpf(fmaf(Pl, Qh, EPS81));
            }
          }
        }
      },
      std::make_integer_sequence<int, NSTEP>{});

  // wave reduction, one atomic per wave
#pragma unroll
  for (int off = 32; off > 0; off >>= 1) acc += __shfl_down(acc, off, 64);
  if (lane == 0) atomicAdd(accum, acc);
}

__global__ void finalize(const float* __restrict__ ws, float* __restrict__ out) {
  out[0] = -ws[0] * (1.0f / (float)((size_t)BATCH * H * W));
}

extern "C" void kernel_launch(void* const* d_in, const int* in_sizes, int n_in,
                              void* d_out, int out_size, void* d_ws, size_t ws_size,
                              hipStream_t stream) {
  const float* I = (const float*)d_in[0];
  const float* J = (const float*)d_in[1];
  float* out = (float*)d_out;
  float* acc = (float*)d_ws;

  zero_accum<<<1, 1, 0, stream>>>(acc);
  ncc_stream<<<BATCH * NBAND, 64, 0, stream>>>(I, J, acc);
  finalize<<<1, 1, 0, stream>>>(acc, out);
}

// Round 5
// 52.611 us; speedup vs baseline: 1.3901x; 1.0200x over previous
//
#include <hip/hip_runtime.h>
#include <utility>

// NCC loss, streaming: full-row C=8, (I,J)-packed fp16, INLINE-ASM PIPELINE v3.
// I,J fp32 (32,1,512,512), 9x9 box, zero-pad, /81.
// History: R21 42.3us (YB=16, prefetch-1 convoy, VALUBusy 16%, ~3.3KB/wave in
// flight ~ marginal vs BDP). R22 source ring FAILED (compiler sank issues).
// R23 2-wave FAILED (convoy TLP-invariant). R24 asm D=6 NaN (spilled pending
// asm-load dests). R25 asm D=4 + d9->LDS: VGPR=256 cap, 15MB scratch writes
// -> spill traffic + vmcnt pollution, 53.7us; pipeline never ran clean.
// R26: BOTH rings (rg, d9) in LDS (36KB; 4 blk/CU x 36KB = 144 <= 160KB, occ
// unchanged). Peak VGPR ~140: buffers(64) + V/vpq/vr(24) + transients. Per
// step +6 lane-stride-16B ds ops (conflict-free, lgkmcnt-tracked by compiler;
// vmcnt literals stay exact). Steady 12-16 loads in flight (16KB/wave, ~16MB
// aggregate = 3-5x BDP -> HBM should saturate). Consume at literal vmcnt(12),
// tail 12/8/4/0; every waitcnt + sched_barrier(0) (rule #18). Volatile-asm
// mutual order pins issue schedule -> structurally un-sinkable.

constexpr int BATCH = 32;
constexpr int H = 512, W = 512;
constexpr int YB = 16;
constexpr int NBAND = H / YB;   // 32
constexpr int NSTEP = YB + 16;  // 32 raw rows yb-8 .. yb+23
constexpr int PFD = 4;          // prefetch distance (rows); 4 loads/row
constexpr float EPS81 = 81.0f * 81.0f * 1e-5f;  // ncc = R^2/(P*Q+EPS81)

using h2 = __attribute__((ext_vector_type(2))) _Float16;
using f4 = __attribute__((ext_vector_type(4))) float;
using u4 = __attribute__((ext_vector_type(4))) unsigned int;

__global__ void zero_accum(float* ws) { ws[0] = 0.0f; }

__device__ __forceinline__ h2 up1(h2 x) {  // lane i <- i-1 (wave_shr:1), edge=0
  return __builtin_bit_cast(
      h2, __builtin_amdgcn_update_dpp(0, __builtin_bit_cast(int, x), 0x138, 0xF,
                                      0xF, true));
}
__device__ __forceinline__ h2 dn1(h2 x) {  // lane i <- i+1 (wave_shl:1), edge=0
  return __builtin_bit_cast(
      h2, __builtin_amdgcn_update_dpp(0, __builtin_bit_cast(int, x), 0x130, 0xF,
                                      0xF, true));
}
// pack (I,J) -> h2 (RTZ) then AND-mask (wave-uniform y zero-pad)
__device__ __forceinline__ h2 pkm(float lo, float hi, unsigned m) {
  const unsigned u =
      __builtin_bit_cast(unsigned, __builtin_amdgcn_cvt_pkrtz(lo, hi)) & m;
  return __builtin_bit_cast(h2, u);
}
__device__ __forceinline__ h2 swp(h2 x) {  // swap halves (folds to op_sel)
  return __builtin_shufflevector(x, x, 1, 0);
}

// Two async 16B loads from p / p+16B. asm => invisible to the compiler's
// scheduler (can't be sunk to use) and waitcnt pass (no auto vmcnt(0)).
__device__ __forceinline__ void gload2(const float* p, f4& a, f4& b) {
  asm volatile(
      "global_load_dwordx4 %0, %2, off\n\t"
      "global_load_dwordx4 %1, %2, off offset:16"
      : "=&v"(a), "=&v"(b)
      : "v"(p));
}

// Hand-counted wait + rule-#18 fence (consumers may not hoist above).
template <int N>
__device__ __forceinline__ void waitcnt_vm() {
  asm volatile("s_waitcnt vmcnt(%0)" ::"i"(N) : "memory");
  __builtin_amdgcn_sched_barrier(0);
}

template <class F, int... Ks>
__device__ __forceinline__ void unroll_steps(F&& f,
                                             std::integer_sequence<int, Ks...>) {
  (f(std::integral_constant<int, Ks>{}), ...);
}

// 9-tap centered window sums, 8 contiguous cols/lane (whole 512-col row).
__device__ __forceinline__ void tap8(const h2 u[8], h2 O[8]) {
  const h2 P0 = u[0], P1 = P0 + u[1], P2 = P1 + u[2], P3 = P2 + u[3],
           P4 = P3 + u[4], P5 = P4 + u[5], P6 = P5 + u[6], T = P6 + u[7];
  const h2 UP3 = up1(P3), UP4 = up1(P4), UP5 = up1(P5), UP6 = up1(P6), UT = up1(T);
  const h2 DP0 = dn1(P0), DP1 = dn1(P1), DP2 = dn1(P2), DP3 = dn1(P3);
  O[0] = (UT - UP3) + P4;
  O[1] = (UT - UP4) + P5;
  O[2] = (UT - UP5) + P6;
  O[3] = (UT - UP6) + T;
  O[4] = T + DP0;
  O[5] = (T - P0) + DP1;
  O[6] = (T - P1) + DP2;
  O[7] = (T - P2) + DP3;
}

__global__ __launch_bounds__(64, 1) void ncc_stream(const float* __restrict__ I,
                                                    const float* __restrict__ J,
                                                    float* __restrict__ accum) {
  const int lane = threadIdx.x;
  const int blk = blockIdx.x;
  const int band = blk & (NBAND - 1);
  const int b = blk >> 5;  // batch 0..31
  const int yb = band * YB;
  const int x0 = 8 * lane;
  const h2 zero2 = {_Float16(0.0f), _Float16(0.0f)};
  const h2 ninv81 = {_Float16(-1.0f / 81.0f), _Float16(-1.0f / 81.0f)};

  const float* __restrict__ Ib = I + (size_t)b * (H * W);
  const float* __restrict__ Jb = J + (size_t)b * (H * W);

  // Rings live in LDS: [slot][half][lane] x 16B. Lane-stride 16B ->
  // conflict-free ds_read_b128/ds_write_b128. Single wave: no barriers.
  __shared__ u4 rgs[9][2][64];  // raw ring: packed (I, J) rows
  __shared__ u4 d9s[9][2][64];  // dI/dJ ring

  h2 V[8];    // running vertical sum of raw
  h2 vpq[8];  // (sum dI^2, sum dJ^2)
  h2 vr[8];   // (sum dI*dJ, same)
#pragma unroll
  for (int c = 0; c < 8; ++c) { V[c] = zero2; vpq[c] = zero2; vr[c] = zero2; }
  const u4 zero4 = {0u, 0u, 0u, 0u};
#pragma unroll
  for (int s = 0; s < 9; ++s) {
    rgs[s][0][lane] = zero4;
    rgs[s][1][lane] = zero4;
    d9s[s][0][lane] = zero4;
    d9s[s][1][lane] = zero4;
  }
  float acc = 0.f;

  // PFD-slot load ring; slot index K%PFD static after template unroll.
  f4 bI0[PFD], bI1[PFD], bJ0[PFD], bJ1[PFD];

  // Prologue: issue rows yb-8 .. yb-8+PFD-1 (lower clamp only; max 491).
#pragma unroll
  for (int j = 0; j < PFD; ++j) {
    const int y0 = yb - 8 + j;
    const int yc0 = y0 < 0 ? 0 : y0;
    const int off0 = yc0 * W + x0;
    gload2(Ib + off0, bI0[j], bI1[j]);
    gload2(Jb + off0, bJ0[j], bJ1[j]);
  }

  // k=0..31: y = yb-8+k. k>=8: stage1 at m=y-4. k>=16: stage2 + output o=y-8.
  unroll_steps(
      [&](auto kc) {
        constexpr int K = decltype(kc)::value;
        constexpr int si = K % 9;        // data ring slot
        constexpr int t = (si + 5) % 9;  // center slot
        constexpr int sl = K % PFD;      // load ring slot
        constexpr int REM = NSTEP - 1 - K;
        constexpr int ALW = (REM < PFD - 1 ? REM : PFD - 1) * 4;
        const int y = yb - 8 + K;
        const unsigned msk = ((y >= 0) & (y < H)) ? 0xFFFFFFFFu : 0u;

        // 0) wait until slot sl's 4 loads (issued PFD steps ago) are done;
        //    leaves ALW (steady 12) in flight.
        waitcnt_vm<ALW>();

        // 1) consume slot sl: pack (I,J), AND-mask y-pad
        h2 na[8];
        na[0] = pkm(bI0[sl].x, bJ0[sl].x, msk);
        na[1] = pkm(bI0[sl].y, bJ0[sl].y, msk);
        na[2] = pkm(bI0[sl].z, bJ0[sl].z, msk);
        na[3] = pkm(bI0[sl].w, bJ0[sl].w, msk);
        na[4] = pkm(bI1[sl].x, bJ1[sl].x, msk);
        na[5] = pkm(bI1[sl].y, bJ1[sl].y, msk);
        na[6] = pkm(bI1[sl].z, bJ1[sl].z, msk);
        na[7] = pkm(bI1[sl].w, bJ1[sl].w, msk);

        // 2) reissue slot sl for row y+PFD (clamped addr; mask fixes values)
        if constexpr (K + PFD < NSTEP) {
          const int yn = y + PFD;
          const int ycn = yn < 0 ? 0 : (yn > H - 1 ? H - 1 : yn);
          const int offn = ycn * W + x0;
          gload2(Ib + offn, bI0[sl], bI1[sl]);
          gload2(Jb + offn, bJ0[sl], bJ1[sl]);
        }

        // 3) vertical running sum: evict slot si (row y-9) from LDS, write new
        {
          const u4 ro0 = rgs[si][0][lane];
          const u4 ro1 = rgs[si][1][lane];
          u4 nv0, nv1;
#pragma unroll
          for (int c = 0; c < 8; ++c) {
            const h2 old = __builtin_bit_cast(h2, c < 4 ? ro0[c] : ro1[c - 4]);
            V[c] += na[c] - old;
            const unsigned du = __builtin_bit_cast(unsigned, na[c]);
            if (c < 4) nv0[c] = du; else nv1[c - 4] = du;
          }
          rgs[si][0][lane] = nv0;
          rgs[si][1][lane] = nv1;
        }

        if constexpr (K >= 8) {
          const int m = y - 4;
          const u4 ov0 = d9s[t][0][lane];  // old d (evicted row), c=0..3
          const u4 ov1 = d9s[t][1][lane];  // c=4..7
          if ((m >= 0) & (m < H)) {        // wave-uniform
            const u4 rt0 = rgs[t][0][lane];  // center raw row (I,J)
            const u4 rt1 = rgs[t][1][lane];
            h2 M[8];
            tap8(V, M);
            u4 nv0, nv1;
#pragma unroll
            for (int c = 0; c < 8; ++c) {
              const h2 rgt =
                  __builtin_bit_cast(h2, c < 4 ? rt0[c] : rt1[c - 4]);
              const h2 d = M[c] * ninv81 + rgt;  // (dI, dJ)
              const h2 o =
                  __builtin_bit_cast(h2, c < 4 ? ov0[c] : ov1[c - 4]);
              vpq[c] += d * d - o * o;           // (dI^2, dJ^2)
              vr[c] += d * swp(d) - o * swp(o);  // (dI*dJ, dI*dJ)
              const unsigned du = __builtin_bit_cast(unsigned, d);
              if (c < 4) nv0[c] = du; else nv1[c - 4] = du;
            }
            d9s[t][0][lane] = nv0;
            d9s[t][1][lane] = nv1;
          } else {  // m outside image: dI=dJ=0, eviction-only
#pragma unroll
            for (int c = 0; c < 8; ++c) {
              const h2 o =
                  __builtin_bit_cast(h2, c < 4 ? ov0[c] : ov1[c - 4]);
              vpq[c] -= o * o;
              vr[c] -= o * swp(o);
            }
            d9s[t][0][lane] = zero4;
            d9s[t][1][lane] = zero4;
          }

          if constexpr (K >= 16) {
            h2 P[8], R[8];
            tap8(vpq, P);  // (81^2 varI, 81^2 varJ) pre-scale
            tap8(vr, R);   // (81^2 cov, same)
#pragma unroll
            for (int c = 0; c < 8; ++c) {
              const float Pl = (float)P[c][0], Qh = (float)P[c][1];
              const float Rl = (float)R[c][0];
              acc += (Rl * Rl) * __builtin_amdgcn_rcpf(fmaf(Pl, Qh, EPS81));
            }
          }
        }
      },
      std::make_integer_sequence<int, NSTEP>{});

  // wave reduction, one atomic per wave
#pragma unroll
  for (int off = 32; off > 0; off >>= 1) acc += __shfl_down(acc, off, 64);
  if (lane == 0) atomicAdd(accum, acc);
}

__global__ void finalize(const float* __restrict__ ws, float* __restrict__ out) {
  out[0] = -ws[0] * (1.0f / (float)((size_t)BATCH * H * W));
}

extern "C" void kernel_launch(void* const* d_in, const int* in_sizes, int n_in,
                              void* d_out, int out_size, void* d_ws, size_t ws_size,
                              hipStream_t stream) {
  const float* I = (const float*)d_in[0];
  const float* J = (const float*)d_in[1];
  float* out = (float*)d_out;
  float* acc = (float*)d_ws;

  zero_accum<<<1, 1, 0, stream>>>(acc);
  ncc_stream<<<BATCH * NBAND, 64, 0, stream>>>(I, J, acc);
  finalize<<<1, 1, 0, stream>>>(acc, out);
}